// Round 6
// baseline (192.693 us; speedup 1.0000x reference)
//
#include <hip/hip_runtime.h>
#include <math.h>

#define N 8192
#define C 10
#define NUM_ITERS 5
#define FBLOCK 1024        /* 16 waves per block, 1 block/CU, 4 waves/SIMD */
#define IBLK 32            /* i's per block */
#define NBLK (N / IBLK)    /* 256 blocks = 1 per CU */
#define JW (N / 16)        /* 512 j's per wave (contiguous) */
#define NS (JW / 32)       /* 16 s-iters per wave, 32 j's each */
#define LOG2E 1.44269504088896340736f
#define C3 (LOG2E / 64.0f)

typedef _Float16 half8 __attribute__((ext_vector_type(8)));
typedef _Float16 half4 __attribute__((ext_vector_type(4)));
typedef _Float16 half2 __attribute__((ext_vector_type(2)));
typedef float f32x4 __attribute__((ext_vector_type(4)));

// ws layout:
//   ajs half8[N]  : j-side spatial aug features   [f*C3 x3, 0, 0,0,-h3*C3, 1]
//   ajb half8[N]  : j-side bilateral aug features [f*L2E x6, -h6*L2E, 1]
//   pf0 f16[16][N]: softmax probs (ping)  rows 10..15 zero
//   pf1 f16[16][N]: softmax probs (pong)  rows 10..15 zero
#define WS_AJS 0
#define WS_AJB (N * 16)
#define WS_PF0 (N * 32)
#define WS_PF1 (N * 64)

static __device__ __forceinline__ half4 expcvt(f32x4 d) {
    float e0 = __builtin_amdgcn_exp2f(d[0]);
    float e1 = __builtin_amdgcn_exp2f(d[1]);
    float e2 = __builtin_amdgcn_exp2f(d[2]);
    float e3 = __builtin_amdgcn_exp2f(d[3]);
    half2 lo = __builtin_bit_cast(half2, __builtin_amdgcn_cvt_pkrtz(e0, e1));
    half2 hi = __builtin_bit_cast(half2, __builtin_amdgcn_cvt_pkrtz(e2, e3));
    half4 r = {lo[0], lo[1], hi[0], hi[1]};
    return r;
}

// once per launch: aug features + softmax(unaries) -> pf0; zero rows 10..15 of both pf
__global__ __launch_bounds__(256) void init_kernel(
    const float* __restrict__ unaries, const float* __restrict__ feat,
    half8* __restrict__ ajs8, half8* __restrict__ ajb8,
    _Float16* __restrict__ pf0, _Float16* __restrict__ pf1) {
    int n = blockIdx.x * 256 + threadIdx.x;
    float f6[6];
#pragma unroll
    for (int d = 0; d < 6; ++d) f6[d] = feat[d * N + n];
    float h3 = 0.5f * (f6[0] * f6[0] + f6[1] * f6[1] + f6[2] * f6[2]);
    float h6v = h3 + 0.5f * (f6[3] * f6[3] + f6[4] * f6[4] + f6[5] * f6[5]);
    half8 a = {};
    a[0] = (_Float16)(f6[0] * C3);
    a[1] = (_Float16)(f6[1] * C3);
    a[2] = (_Float16)(f6[2] * C3);
    a[6] = (_Float16)(-h3 * C3);
    a[7] = (_Float16)1.0f;
    ajs8[n] = a;
    half8 b;
#pragma unroll
    for (int d = 0; d < 6; ++d) b[d] = (_Float16)(f6[d] * LOG2E);
    b[6] = (_Float16)(-h6v * LOG2E);
    b[7] = (_Float16)1.0f;
    ajb8[n] = b;

    float q[C];
#pragma unroll
    for (int c = 0; c < C; ++c) q[c] = unaries[c * N + n];
    float m = q[0];
#pragma unroll
    for (int c = 1; c < C; ++c) m = fmaxf(m, q[c]);
    float e[C], s = 0.0f;
#pragma unroll
    for (int c = 0; c < C; ++c) {
        e[c] = __builtin_amdgcn_exp2f((q[c] - m) * LOG2E);
        s += e[c];
    }
    float inv = 1.0f / s;
#pragma unroll
    for (int c = 0; c < C; ++c) pf0[c * N + n] = (_Float16)(e[c] * inv);
#pragma unroll
    for (int c = C; c < 16; ++c) {
        pf0[c * N + n] = (_Float16)0.0f;
        pf1[c * N + n] = (_Float16)0.0f;
    }
}

// one dispatch per CRF iteration: block owns 32 i's; 16 waves sweep all N j's,
// wave w free-runs over its contiguous 512-j range with direct L2->register
// operand fetch (1-deep prefetch). NO barriers in the main loop. LDS only for
// the final cross-wave reduction. pf double-buffered across dispatches.
__global__ __launch_bounds__(FBLOCK, 4) void fused_kernel(
    const float* __restrict__ unaries, const float* __restrict__ feat,
    const float* __restrict__ SW, const float* __restrict__ BW,
    const float* __restrict__ CM,
    const half4* __restrict__ ajs_g, const half4* __restrict__ ajb_g,
    const _Float16* __restrict__ pf_in, _Float16* __restrict__ pf_out,
    float* __restrict__ out, int is_last) {
    __shared__ float rbuf[16 * 1024];   // 64 KB
    int t = threadIdx.x;
    int i0 = blockIdx.x * IBLK;
    int lane = t & 63;
    int w = t >> 6;            // wave id 0..15
    int il = lane & 15;
    int quad = lane >> 4;
    int h = quad & 1;
    bool klo = (quad < 2);
    const half4 hz = {};

    // ---- i-side B1 fragments (32 i's, 2 subtiles of 16) ----
    half4 b1s0, b1s1, b1b0, b1b1;
#pragma unroll
    for (int s = 0; s < 2; ++s) {
        int i = i0 + s * 16 + il;
        float g0 = feat[0 * N + i], g1 = feat[1 * N + i], g2 = feat[2 * N + i];
        float g3 = feat[3 * N + i], g4 = feat[4 * N + i], g5 = feat[5 * N + i];
        float h3 = 0.5f * (g0 * g0 + g1 * g1 + g2 * g2);
        float h6v = h3 + 0.5f * (g3 * g3 + g4 * g4 + g5 * g5);
        half4 slo = {(_Float16)g0, (_Float16)g1, (_Float16)g2, (_Float16)0.0f};
        half4 shi = {(_Float16)0.0f, (_Float16)0.0f, (_Float16)1.0f, (_Float16)(-h3 * C3)};
        half4 blo = {(_Float16)g0, (_Float16)g1, (_Float16)g2, (_Float16)g3};
        half4 bhi = {(_Float16)g4, (_Float16)g5, (_Float16)1.0f, (_Float16)(-h6v * LOG2E)};
        half4 vs = klo ? (h ? shi : slo) : hz;
        half4 vb = klo ? (h ? bhi : blo) : hz;
        if (s == 0) { b1s0 = vs; b1b0 = vb; } else { b1s1 = vs; b1b1 = vb; }
    }

    f32x4 as0 = {0.f, 0.f, 0.f, 0.f}, as1 = {0.f, 0.f, 0.f, 0.f};
    f32x4 ab0 = {0.f, 0.f, 0.f, 0.f}, ab1 = {0.f, 0.f, 0.f, 0.f};
    const f32x4 zero = {0.f, 0.f, 0.f, 0.f};

    int wbase = w * JW;
    // GEMM-1 A-side fragments: lanes with quad>=2 (k=8..15) may hold garbage —
    // safe because the B-side (b1*) is exactly zero there (finite*0 == 0).

    // ---- prologue: load s-iter 0 operands ----
    half4 cvs0 = ajs_g[(wbase + il) * 2 + h];
    half4 cvb0 = ajb_g[(wbase + il) * 2 + h];
    half4 cvs1 = ajs_g[(wbase + 16 + il) * 2 + h];
    half4 cvb1 = ajb_g[(wbase + 16 + il) * 2 + h];
    half4 cp0 = *(const half4*)&pf_in[il * N + wbase + quad * 4];
    half4 cp1 = *(const half4*)&pf_in[il * N + wbase + 16 + quad * 4];

    for (int k = 0; k < NS; ++k) {
        // issue next s-iter's loads (wrap on last iter; harmless L2 hit)
        int jn = wbase + ((k + 1) & (NS - 1)) * 32;
        half4 nvs0 = ajs_g[(jn + il) * 2 + h];
        half4 nvb0 = ajb_g[(jn + il) * 2 + h];
        half4 nvs1 = ajs_g[(jn + 16 + il) * 2 + h];
        half4 nvb1 = ajb_g[(jn + 16 + il) * 2 + h];
        half4 np0 = *(const half4*)&pf_in[il * N + jn + quad * 4];
        half4 np1 = *(const half4*)&pf_in[il * N + jn + 16 + quad * 4];

        // GEMM-1: S^T[j][i] in C/D layout (8 independent chains)
        f32x4 d0 = __builtin_amdgcn_mfma_f32_16x16x16f16(cvs0, b1s0, zero, 0, 0, 0);
        f32x4 d1 = __builtin_amdgcn_mfma_f32_16x16x16f16(cvs0, b1s1, zero, 0, 0, 0);
        f32x4 d2 = __builtin_amdgcn_mfma_f32_16x16x16f16(cvb0, b1b0, zero, 0, 0, 0);
        f32x4 d3 = __builtin_amdgcn_mfma_f32_16x16x16f16(cvb0, b1b1, zero, 0, 0, 0);
        f32x4 d4 = __builtin_amdgcn_mfma_f32_16x16x16f16(cvs1, b1s0, zero, 0, 0, 0);
        f32x4 d5 = __builtin_amdgcn_mfma_f32_16x16x16f16(cvs1, b1s1, zero, 0, 0, 0);
        f32x4 d6 = __builtin_amdgcn_mfma_f32_16x16x16f16(cvb1, b1b0, zero, 0, 0, 0);
        f32x4 d7 = __builtin_amdgcn_mfma_f32_16x16x16f16(cvb1, b1b1, zero, 0, 0, 0);

        half4 w0 = expcvt(d0), w1 = expcvt(d1), w2 = expcvt(d2), w3 = expcvt(d3);
        half4 w4 = expcvt(d4), w5 = expcvt(d5), w6 = expcvt(d6), w7 = expcvt(d7);

        // GEMM-2: out[i][c] += w[i][j] * p[c][j]
        as0 = __builtin_amdgcn_mfma_f32_16x16x16f16(w0, cp0, as0, 0, 0, 0);
        as1 = __builtin_amdgcn_mfma_f32_16x16x16f16(w1, cp0, as1, 0, 0, 0);
        ab0 = __builtin_amdgcn_mfma_f32_16x16x16f16(w2, cp0, ab0, 0, 0, 0);
        ab1 = __builtin_amdgcn_mfma_f32_16x16x16f16(w3, cp0, ab1, 0, 0, 0);
        as0 = __builtin_amdgcn_mfma_f32_16x16x16f16(w4, cp1, as0, 0, 0, 0);
        as1 = __builtin_amdgcn_mfma_f32_16x16x16f16(w5, cp1, as1, 0, 0, 0);
        ab0 = __builtin_amdgcn_mfma_f32_16x16x16f16(w6, cp1, ab0, 0, 0, 0);
        ab1 = __builtin_amdgcn_mfma_f32_16x16x16f16(w7, cp1, ab1, 0, 0, 0);

        cvs0 = nvs0; cvb0 = nvb0; cvs1 = nvs1; cvb1 = nvb1;
        cp0 = np0; cp1 = np1;
    }

    // ---- cross-wave reduction in LDS (conflict-free dump: r*64+lane) ----
    {
        float* rb = rbuf + w * 1024;
#pragma unroll
        for (int r = 0; r < 4; ++r) {
            rb[r * 64 + lane]       = as0[r];
            rb[256 + r * 64 + lane] = as1[r];
            rb[512 + r * 64 + lane] = ab0[r];
            rb[768 + r * 64 + lane] = ab1[r];
        }
    }
    __syncthreads();
    {
        float tot = 0.f;
#pragma unroll
        for (int w2 = 0; w2 < 16; ++w2) tot += rbuf[w2 * 1024 + t];
        // in-place: position t is only ever read by thread t (w2=0 term)
        rbuf[t] = tot;
    }
    __syncthreads();

    // ---- combine + compatibility + softmax for this block's 32 i's ----
    if (t < IBLK) {
        int i = i0 + t;
        int sub = t >> 4, ql = (t & 15) >> 2, rr = t & 3;
        float sp[C], bl[C];
#pragma unroll
        for (int c = 0; c < C; ++c) {
            int base = sub * 256 + rr * 64 + ql * 16 + c;
            sp[c] = rbuf[base];
            bl[c] = rbuf[base + 512];
        }
        float msg[C];
#pragma unroll
        for (int c = 0; c < C; ++c) {
            float m = 0.f;
#pragma unroll
            for (int k = 0; k < C; ++k)
                m += SW[c * C + k] * sp[k] + BW[c * C + k] * bl[k];
            msg[c] = m;
        }
        float qq[C];
#pragma unroll
        for (int c = 0; c < C; ++c) {
            float pw = 0.f;
#pragma unroll
            for (int k = 0; k < C; ++k) pw += CM[c * C + k] * msg[k];
            qq[c] = unaries[c * N + i] - pw;
        }
        if (is_last) {
#pragma unroll
            for (int c = 0; c < C; ++c) out[c * N + i] = qq[c];
        } else {
            float m = qq[0];
#pragma unroll
            for (int c = 1; c < C; ++c) m = fmaxf(m, qq[c]);
            float e[C], s = 0.0f;
#pragma unroll
            for (int c = 0; c < C; ++c) {
                e[c] = __builtin_amdgcn_exp2f((qq[c] - m) * LOG2E);
                s += e[c];
            }
            float inv = 1.0f / s;
#pragma unroll
            for (int c = 0; c < C; ++c) pf_out[c * N + i] = (_Float16)(e[c] * inv);
        }
    }
}

extern "C" void kernel_launch(void* const* d_in, const int* in_sizes, int n_in,
                              void* d_out, int out_size, void* d_ws, size_t ws_size,
                              hipStream_t stream) {
    const float* unaries = (const float*)d_in[0];   // [10, 8192]
    const float* feat    = (const float*)d_in[1];   // [6, 8192]
    const float* SW      = (const float*)d_in[2];   // [10,10]
    const float* BW      = (const float*)d_in[3];   // [10,10]
    const float* CM      = (const float*)d_in[4];   // [10,10]
    float* out = (float*)d_out;

    char* ws = (char*)d_ws;
    half8* ajs    = (half8*)(ws + WS_AJS);
    half8* ajb    = (half8*)(ws + WS_AJB);
    _Float16* pf0 = (_Float16*)(ws + WS_PF0);
    _Float16* pf1 = (_Float16*)(ws + WS_PF1);

    init_kernel<<<N / 256, 256, 0, stream>>>(unaries, feat, ajs, ajb, pf0, pf1);
    const _Float16* pin = pf0;
    _Float16* pout = pf1;
    for (int it = 1; it <= NUM_ITERS; ++it) {
        fused_kernel<<<NBLK, FBLOCK, 0, stream>>>(
            unaries, feat, SW, BW, CM, (const half4*)ajs, (const half4*)ajb,
            pin, pout, out, it == NUM_ITERS ? 1 : 0);
        const _Float16* tmp = pout;
        pout = (_Float16*)pin;
        pin = tmp;
    }
}